// Round 11
// baseline (208.749 us; speedup 1.0000x reference)
//
#include <hip/hip_runtime.h>

// ============================================================================
// Piecewise-constant LUT, v5b: wave-parallel build + NT-store apply.
// (R10 fix: NT store through clang ext_vector_type — HIP float4 is a struct
// and __builtin_nontemporal_store rejects it.)
//
// Reference per element (fp32; chain validated bit-exact R0-R8):
//   a = |x|; v = a; z = 0; acc = 0
//   for t: v = fmaf(-z,h[t],v); z = (v > T[t]); acc = fmaf(z,d[t],acc)
//   out = acc * sign(x)
//
// Endpoint-mask rule (validated R6-R8, absmax 0): equal 16-bit predicate
// masks at the endpoints of a bit-space interval => mask constant inside.
// Value depends only on the mask => exact per-segment value.
//
// Build: Phase A (16x256) classifies 4096 bins (2 predmasks each). Phase B:
// one wave per mixed bin; 64 lanes sweep all interior points of each mixed
// 144-ULP gap (3 probes/lane) -> all transitions located, no serial search.
// Apply: flat LDS path (R8) + nontemporal stores (out never re-read).
// Overflow -> flag -> wave-uniform direct-scan fallback.
// ============================================================================

#define BIN_B0 0x3D800000u   // bits(0.0625)
#define BIN_B1 0x3FC00000u   // bits(1.5)
#define BIN_RANGE 0x02400000u
#define NBIN 4096
#define GAP 144u             // 9216 / 64
#define CMAX 15
#define BP_CAP 2048          // pool words (8 KB)
#define MIXEDTAG 0xFFFFFFFFu

#define W_CNT 0
#define W_FLAG 1
#define W_LO 2
#define W_HI 3
#define W_LUT 4
#define W_BP (W_LUT + NBIN)
#define WS_WORDS (W_BP + BP_CAP)   // 6148 words = 24.6 KB

typedef float f32x4v __attribute__((ext_vector_type(4)));

__device__ __forceinline__ int predmask16(float a, const float* __restrict__ hh,
                                          const float* __restrict__ TT) {
    float v = a, z = 0.0f;
    int m = 0;
#pragma unroll
    for (int k = 0; k < 16; ++k) {
        v = fmaf(-z, hh[k], v);
        int zb = (v > TT[k]) ? 1 : 0;
        z = zb ? 1.0f : 0.0f;
        m |= zb << k;
    }
    return m;
}

__device__ __forceinline__ unsigned int valbits(int m, const float* __restrict__ dd) {
    float acc = 0.0f;
#pragma unroll
    for (int k = 0; k < 16; ++k)
        acc = ((m >> k) & 1) ? (acc + dd[k]) : acc;  // fl(acc+d) == fmaf(1,d,acc)
    return __float_as_uint(acc);
}

__device__ __forceinline__ float scan_exact(unsigned int ab, const float* __restrict__ hh,
                                            const float* __restrict__ dd,
                                            const float* __restrict__ TT) {
    float v = __uint_as_float(ab), z = 0.0f, acc = 0.0f;
#pragma unroll
    for (int k = 0; k < 16; ++k) {
        v = fmaf(-z, hh[k], v);
        z = (v > TT[k]) ? 1.0f : 0.0f;
        acc = fmaf(z, dd[k], acc);
    }
    return acc;
}

// ------------------------------------------------------------ K1: classify
__global__ __launch_bounds__(256) void snn_classify(
    const float* __restrict__ h, const float* __restrict__ d,
    const float* __restrict__ T, unsigned int* __restrict__ ws) {
    const int u = blockIdx.x * 256 + threadIdx.x;
    float hh[16], dd[16], TT[16];
#pragma unroll
    for (int k = 0; k < 16; ++k) { hh[k] = h[k]; dd[k] = d[k]; TT[k] = T[k]; }

    if (u == 0) {  // single writer: counters + boundary regions (no race)
        ws[W_CNT] = 0u;
        unsigned int flag = 0u;
        int mA = predmask16(__uint_as_float(0u), hh, TT);
        int mB = predmask16(__uint_as_float(BIN_B0 - 1u), hh, TT);
        if (mA == mB) ws[W_LO] = valbits(mA, dd); else { ws[W_LO] = 0u; flag = 1u; }
        mA = predmask16(__uint_as_float(BIN_B1), hh, TT);
        mB = predmask16(__uint_as_float(0x7F7FFFFFu), hh, TT);
        if (mA == mB) ws[W_HI] = valbits(mA, dd); else { ws[W_HI] = 0u; flag = 1u; }
        ws[W_FLAG] = flag;
    }
    if (u >= NBIN) return;

    const unsigned int Lb = BIN_B0 + (unsigned int)u * 9216u;
    const int mL = predmask16(__uint_as_float(Lb), hh, TT);
    const int mH = predmask16(__uint_as_float(Lb + 9215u), hh, TT);
    ws[W_LUT + u] = (mL == mH) ? valbits(mL, dd) : MIXEDTAG;
}

// ------------------------------------------------------------- K2: refine
__global__ __launch_bounds__(64) void snn_refine(
    const float* __restrict__ h, const float* __restrict__ d,
    const float* __restrict__ T, unsigned int* __restrict__ ws) {
    const unsigned int b = blockIdx.x;
    if (ws[W_LUT + b] != MIXEDTAG) return;  // clean bin: exit fast

    __shared__ unsigned int posS[CMAX + 1];
    __shared__ int mskS[CMAX + 1];
    __shared__ int cntS;
    const int l = threadIdx.x;
    if (l == 0) cntS = 0;
    __syncthreads();

    float hh[16], dd[16], TT[16];
#pragma unroll
    for (int k = 0; k < 16; ++k) { hh[k] = h[k]; dd[k] = d[k]; TT[k] = T[k]; }

    const unsigned int Lb = BIN_B0 + b * 9216u;
    // level 0: lane l probes Lb + min((l+1)*GAP, 9215); also mL (uniform).
    const int mL = predmask16(__uint_as_float(Lb), hh, TT);
    unsigned int po = (unsigned int)(l + 1) * GAP;
    po = (po > 9215u) ? 9215u : po;
    const int ml = predmask16(__uint_as_float(Lb + po), hh, TT);
    int mprev = __shfl_up(ml, 1);
    if (l == 0) mprev = mL;
    const bool mixed = (mprev != ml);
    unsigned long long bal = __ballot(mixed);

    while (bal) {
        const int g = __ffsll((long long)bal) - 1;
        bal &= bal - 1ull;
        const unsigned int gstart = Lb + (unsigned int)g * GAP;
        unsigned int gend = (unsigned int)(g + 1) * GAP;
        gend = (gend > 9215u) ? 9215u : gend;
        const unsigned int width = (Lb + gend) - gstart;  // 143 or 144
        const int m_glo = __shfl(mprev, g);               // mask at gstart
        // evaluate all interior points gstart+1+k, k = l + 64j  (j=0..2)
        int mk0 = predmask16(__uint_as_float(gstart + 1u + (unsigned int)l), hh, TT);
        int mk1 = predmask16(__uint_as_float(gstart + 65u + (unsigned int)l), hh, TT);
        int mk2 = predmask16(__uint_as_float(gstart + 129u + (unsigned int)l), hh, TT);
        int pm0 = __shfl_up(mk0, 1);
        int pm1 = __shfl_up(mk1, 1);
        int pm2 = __shfl_up(mk2, 1);
        const int w0 = __shfl(mk0, 63);
        const int w1 = __shfl(mk1, 63);
        if (l == 0) { pm0 = m_glo; pm1 = w0; pm2 = w1; }
        // record transitions (pos, mask-after)
        if ((unsigned int)l < width && pm0 != mk0) {
            int s = atomicAdd(&cntS, 1);
            if (s <= CMAX) { posS[s] = gstart + 1u + l; mskS[s] = mk0; }
        }
        if ((unsigned int)(l + 64) < width && pm1 != mk1) {
            int s = atomicAdd(&cntS, 1);
            if (s <= CMAX) { posS[s] = gstart + 65u + l; mskS[s] = mk1; }
        }
        if ((unsigned int)(l + 128) < width && pm2 != mk2) {
            int s = atomicAdd(&cntS, 1);
            if (s <= CMAX) { posS[s] = gstart + 129u + l; mskS[s] = mk2; }
        }
        __syncthreads();
    }
    __syncthreads();

    if (l == 0) {
        int c = cntS;
        if (c < 1 || c > CMAX) {  // impossible-low / overflow -> full fallback
            atomicOr(&ws[W_FLAG], 1u);
            ws[W_LUT + b] = 0u;
        } else {
            for (int i = 1; i < c; ++i) {  // insertion sort by position
                unsigned int p = posS[i];
                int m = mskS[i];
                int j = i - 1;
                while (j >= 0 && posS[j] > p) {
                    posS[j + 1] = posS[j];
                    mskS[j + 1] = mskS[j];
                    --j;
                }
                posS[j + 1] = p;
                mskS[j + 1] = m;
            }
            const unsigned int need = 2u * (unsigned int)c + 1u;
            const unsigned int start = atomicAdd(&ws[W_CNT], need);
            if (start + need > BP_CAP) {
                atomicOr(&ws[W_FLAG], 1u);
                ws[W_LUT + b] = 0u;
            } else {
                const int mLb = predmask16(__uint_as_float(Lb), hh, TT);
                for (int k = 0; k < c; ++k) ws[W_BP + start + k] = posS[k];
                ws[W_BP + start + c] = valbits(mLb, dd);
                for (int j = 0; j < c; ++j)
                    ws[W_BP + start + c + 1 + j] = valbits(mskS[j], dd);
                ws[W_LUT + b] =
                    0x7F800000u | ((unsigned int)c << 19) | start;
            }
        }
    }
}

// ----------------------------------------------------------------- K3: apply
__device__ __forceinline__ float lut_elem(float xe,
                                          const unsigned int* __restrict__ lutS,
                                          const unsigned int* __restrict__ bpS,
                                          unsigned int lo_e, unsigned int hi_e) {
    const unsigned int u = __float_as_uint(xe);
    const unsigned int sb = u & 0x80000000u;
    const unsigned int ab = u & 0x7FFFFFFFu;
    unsigned int t = ab - BIN_B0;                    // wraps if ab < B0
    t = (t > BIN_RANGE - 1u) ? (BIN_RANGE - 1u) : t; // clamp wrap / high
    const unsigned int bin = ((t >> 10) * 58255u) >> 19;  // exact floor(/9216)
    unsigned int eb = lutS[bin];
    eb = (ab < BIN_B0) ? lo_e : eb;
    eb = (ab >= BIN_B1) ? hi_e : eb;
    if ((eb & 0x7F800000u) == 0x7F800000u) {  // multi-segment bin record
        const unsigned int s = eb & 0x7FFFFu;
        const unsigned int c = (eb >> 19) & 0xFu;
        unsigned int j = 0;
        for (unsigned int k = 0; k < c; ++k)
            j += (ab >= bpS[s + k]) ? 1u : 0u;   // bps sorted; j = rank
        eb = bpS[s + c + j];
    }
    const float r = __uint_as_float(eb ^ sb);
    return (xe == 0.0f) ? 0.0f : r;
}

__global__ __launch_bounds__(256) void snn_apply(
    const float* __restrict__ x, const float* __restrict__ h,
    const float* __restrict__ d, const float* __restrict__ T,
    float* __restrict__ out, const unsigned int* __restrict__ ws,
    int n8, int n4, int n) {
    __shared__ unsigned int lutS[NBIN];   // 16 KB
    __shared__ unsigned int bpS[BP_CAP];  // 8 KB
    const int tid = threadIdx.x;

    for (int i = tid; i < NBIN; i += 256) lutS[i] = ws[W_LUT + i];
    for (int i = tid; i < BP_CAP; i += 256) bpS[i] = ws[W_BP + i];
    const unsigned int flag = ws[W_FLAG];
    const unsigned int lo_e = ws[W_LO];
    const unsigned int hi_e = ws[W_HI];
    __syncthreads();

    const float4* __restrict__ x4 = reinterpret_cast<const float4*>(x);
    float4* __restrict__ o4 = reinterpret_cast<float4*>(out);
    const int gtid = blockIdx.x * blockDim.x + tid;
    const int nt = gridDim.x * blockDim.x;

    if (flag == 0u) {  // ---- LUT path (expected) ----
#define APPLY4NT(vv, dst)                                                      \
        {                                                                      \
            f32x4v ov;                                                         \
            ov.x = lut_elem(vv.x, lutS, bpS, lo_e, hi_e);                      \
            ov.y = lut_elem(vv.y, lutS, bpS, lo_e, hi_e);                      \
            ov.z = lut_elem(vv.z, lutS, bpS, lo_e, hi_e);                      \
            ov.w = lut_elem(vv.w, lutS, bpS, lo_e, hi_e);                      \
            __builtin_nontemporal_store(ov, reinterpret_cast<f32x4v*>(dst));   \
        }
        int i = gtid;  // unit = pair of adjacent float4 (R4 skeleton)
        if (i < n8) {
            float4 ca = x4[2 * i], cb = x4[2 * i + 1];
            int nx = i + nt;
            while (nx < n8) {
                float4 pa = x4[2 * nx], pb = x4[2 * nx + 1];
                APPLY4NT(ca, o4 + 2 * i);
                APPLY4NT(cb, o4 + 2 * i + 1);
                ca = pa; cb = pb;
                i = nx; nx += nt;
            }
            APPLY4NT(ca, o4 + 2 * i);
            APPLY4NT(cb, o4 + 2 * i + 1);
        }
        for (int j = n8 * 2 + gtid; j < n4; j += nt) {
            float4 v = x4[j];
            APPLY4NT(v, o4 + j);
        }
        for (int j = n4 * 4 + gtid; j < n; j += nt)
            out[j] = lut_elem(x[j], lutS, bpS, lo_e, hi_e);
#undef APPLY4NT
    } else {  // ---- wave-uniform fallback: direct scan (always correct) ----
        float hh[16], dd[16], TT[16];
#pragma unroll
        for (int k = 0; k < 16; ++k) { hh[k] = h[k]; dd[k] = d[k]; TT[k] = T[k]; }
        for (int j = gtid; j < n4; j += nt) {
            float4 v = x4[j], ov;
            float* pi = &v.x;
            float* po = &ov.x;
#pragma unroll
            for (int e = 0; e < 4; ++e) {
                float xe = pi[e];
                float acc = scan_exact(__float_as_uint(xe) & 0x7FFFFFFFu, hh, dd, TT);
                unsigned int rb =
                    __float_as_uint(acc) ^ (__float_as_uint(xe) & 0x80000000u);
                po[e] = (xe == 0.0f) ? 0.0f : __uint_as_float(rb);
            }
            o4[j] = ov;
        }
        for (int j = n4 * 4 + gtid; j < n; j += nt) {
            float xe = x[j];
            float acc = scan_exact(__float_as_uint(xe) & 0x7FFFFFFFu, hh, dd, TT);
            unsigned int rb = __float_as_uint(acc) ^ (__float_as_uint(xe) & 0x80000000u);
            out[j] = (xe == 0.0f) ? 0.0f : __uint_as_float(rb);
        }
    }
}

// -------------------------------------------- direct fallback (ws too small)
__global__ __launch_bounds__(256) void snn_direct(
    const float* __restrict__ x, const float* __restrict__ h,
    const float* __restrict__ d, const float* __restrict__ T,
    float* __restrict__ out, int n4, int n) {
    float hh[16], dd[16], TT[16];
#pragma unroll
    for (int k = 0; k < 16; ++k) { hh[k] = h[k]; dd[k] = d[k]; TT[k] = T[k]; }
    const float4* __restrict__ x4 = reinterpret_cast<const float4*>(x);
    float4* __restrict__ o4 = reinterpret_cast<float4*>(out);
    const int gtid = blockIdx.x * blockDim.x + threadIdx.x;
    const int nt = gridDim.x * blockDim.x;
    for (int i = gtid; i < n4; i += nt) {
        float4 v = x4[i], ov;
        float* pi = &v.x;
        float* po = &ov.x;
#pragma unroll
        for (int e = 0; e < 4; ++e) {
            float xe = pi[e];
            float acc = scan_exact(__float_as_uint(xe) & 0x7FFFFFFFu, hh, dd, TT);
            unsigned int rb =
                __float_as_uint(acc) ^ (__float_as_uint(xe) & 0x80000000u);
            po[e] = (xe == 0.0f) ? 0.0f : __uint_as_float(rb);
        }
        o4[i] = ov;
    }
    for (int j = n4 * 4 + gtid; j < n; j += nt) {
        float xe = x[j];
        float acc = scan_exact(__float_as_uint(xe) & 0x7FFFFFFFu, hh, dd, TT);
        unsigned int rb = __float_as_uint(acc) ^ (__float_as_uint(xe) & 0x80000000u);
        out[j] = (xe == 0.0f) ? 0.0f : __uint_as_float(rb);
    }
}

extern "C" void kernel_launch(void* const* d_in, const int* in_sizes, int n_in,
                              void* d_out, int out_size, void* d_ws, size_t ws_size,
                              hipStream_t stream) {
    const float* x = (const float*)d_in[0];
    const float* h = (const float*)d_in[1];
    const float* d = (const float*)d_in[2];
    const float* T = (const float*)d_in[3];
    float* out = (float*)d_out;

    const int n = in_sizes[0];
    const int n4 = n / 4;
    const int n8 = n / 8;

    if (ws_size < (size_t)WS_WORDS * 4) {
        int grid = 2048;
        const int needed = (n4 + 255) / 256;
        if (grid > needed) grid = needed > 0 ? needed : 1;
        snn_direct<<<grid, 256, 0, stream>>>(x, h, d, T, out, n4, n);
        return;
    }

    unsigned int* ws = (unsigned int*)d_ws;
    snn_classify<<<NBIN / 256, 256, 0, stream>>>(h, d, T, ws);
    snn_refine<<<NBIN, 64, 0, stream>>>(h, d, T, ws);

    // 24 KB LDS/block -> 6 blocks/CU -> 1536 blocks fills the chip.
    int grid = 1536;
    const int needed = (n8 + 255) / 256;
    if (grid > needed) grid = needed > 0 ? needed : 1;
    snn_apply<<<grid, 256, 0, stream>>>(x, h, d, T, out, ws, n8, n4, n);
}

// Round 12
// 135.298 us; speedup vs baseline: 1.5429x; 1.5429x over previous
//
#include <hip/hip_runtime.h>

// ============================================================================
// Piecewise-constant LUT, v6: wave-parallel build + plain-store apply.
// (R12: single change vs R11 — drop nontemporal stores; R11 showed 1.85x
// write amplification (486MB for 262MB output) and ~2x apply slowdown.)
//
// Reference per element (fp32; chain validated bit-exact R0-R11):
//   a = |x|; v = a; z = 0; acc = 0
//   for t: v = fmaf(-z,h[t],v); z = (v > T[t]); acc = fmaf(z,d[t],acc)
//   out = acc * sign(x)
//
// Endpoint-mask rule (validated R6-R11, absmax 0): equal 16-bit predicate
// masks at the endpoints of a bit-space interval => mask constant inside.
// Value depends only on the mask => exact per-segment value.
//
// Build: classify (4096 bins, 2 predmasks each) + refine (one wave per mixed
// bin; 64 lanes sweep interior points of mixed 144-ULP gaps, 3 probes/lane).
// Apply: flat LDS path, 1 ds_read typical, short sorted-rank loop for mixed
// bins. Overflow -> flag -> wave-uniform direct-scan fallback.
// ============================================================================

#define BIN_B0 0x3D800000u   // bits(0.0625)
#define BIN_B1 0x3FC00000u   // bits(1.5)
#define BIN_RANGE 0x02400000u
#define NBIN 4096
#define GAP 144u             // 9216 / 64
#define CMAX 15
#define BP_CAP 2048          // pool words (8 KB)
#define MIXEDTAG 0xFFFFFFFFu

#define W_CNT 0
#define W_FLAG 1
#define W_LO 2
#define W_HI 3
#define W_LUT 4
#define W_BP (W_LUT + NBIN)
#define WS_WORDS (W_BP + BP_CAP)   // 6148 words = 24.6 KB

__device__ __forceinline__ int predmask16(float a, const float* __restrict__ hh,
                                          const float* __restrict__ TT) {
    float v = a, z = 0.0f;
    int m = 0;
#pragma unroll
    for (int k = 0; k < 16; ++k) {
        v = fmaf(-z, hh[k], v);
        int zb = (v > TT[k]) ? 1 : 0;
        z = zb ? 1.0f : 0.0f;
        m |= zb << k;
    }
    return m;
}

__device__ __forceinline__ unsigned int valbits(int m, const float* __restrict__ dd) {
    float acc = 0.0f;
#pragma unroll
    for (int k = 0; k < 16; ++k)
        acc = ((m >> k) & 1) ? (acc + dd[k]) : acc;  // fl(acc+d) == fmaf(1,d,acc)
    return __float_as_uint(acc);
}

__device__ __forceinline__ float scan_exact(unsigned int ab, const float* __restrict__ hh,
                                            const float* __restrict__ dd,
                                            const float* __restrict__ TT) {
    float v = __uint_as_float(ab), z = 0.0f, acc = 0.0f;
#pragma unroll
    for (int k = 0; k < 16; ++k) {
        v = fmaf(-z, hh[k], v);
        z = (v > TT[k]) ? 1.0f : 0.0f;
        acc = fmaf(z, dd[k], acc);
    }
    return acc;
}

// ------------------------------------------------------------ K1: classify
__global__ __launch_bounds__(256) void snn_classify(
    const float* __restrict__ h, const float* __restrict__ d,
    const float* __restrict__ T, unsigned int* __restrict__ ws) {
    const int u = blockIdx.x * 256 + threadIdx.x;
    float hh[16], dd[16], TT[16];
#pragma unroll
    for (int k = 0; k < 16; ++k) { hh[k] = h[k]; dd[k] = d[k]; TT[k] = T[k]; }

    if (u == 0) {  // single writer: counters + boundary regions (no race)
        ws[W_CNT] = 0u;
        unsigned int flag = 0u;
        int mA = predmask16(__uint_as_float(0u), hh, TT);
        int mB = predmask16(__uint_as_float(BIN_B0 - 1u), hh, TT);
        if (mA == mB) ws[W_LO] = valbits(mA, dd); else { ws[W_LO] = 0u; flag = 1u; }
        mA = predmask16(__uint_as_float(BIN_B1), hh, TT);
        mB = predmask16(__uint_as_float(0x7F7FFFFFu), hh, TT);
        if (mA == mB) ws[W_HI] = valbits(mA, dd); else { ws[W_HI] = 0u; flag = 1u; }
        ws[W_FLAG] = flag;
    }
    if (u >= NBIN) return;

    const unsigned int Lb = BIN_B0 + (unsigned int)u * 9216u;
    const int mL = predmask16(__uint_as_float(Lb), hh, TT);
    const int mH = predmask16(__uint_as_float(Lb + 9215u), hh, TT);
    ws[W_LUT + u] = (mL == mH) ? valbits(mL, dd) : MIXEDTAG;
}

// ------------------------------------------------------------- K2: refine
__global__ __launch_bounds__(64) void snn_refine(
    const float* __restrict__ h, const float* __restrict__ d,
    const float* __restrict__ T, unsigned int* __restrict__ ws) {
    const unsigned int b = blockIdx.x;
    if (ws[W_LUT + b] != MIXEDTAG) return;  // clean bin: exit fast

    __shared__ unsigned int posS[CMAX + 1];
    __shared__ int mskS[CMAX + 1];
    __shared__ int cntS;
    const int l = threadIdx.x;
    if (l == 0) cntS = 0;
    __syncthreads();

    float hh[16], dd[16], TT[16];
#pragma unroll
    for (int k = 0; k < 16; ++k) { hh[k] = h[k]; dd[k] = d[k]; TT[k] = T[k]; }

    const unsigned int Lb = BIN_B0 + b * 9216u;
    const int mL = predmask16(__uint_as_float(Lb), hh, TT);
    unsigned int po = (unsigned int)(l + 1) * GAP;
    po = (po > 9215u) ? 9215u : po;
    const int ml = predmask16(__uint_as_float(Lb + po), hh, TT);
    int mprev = __shfl_up(ml, 1);
    if (l == 0) mprev = mL;
    const bool mixed = (mprev != ml);
    unsigned long long bal = __ballot(mixed);

    while (bal) {
        const int g = __ffsll((long long)bal) - 1;
        bal &= bal - 1ull;
        const unsigned int gstart = Lb + (unsigned int)g * GAP;
        unsigned int gend = (unsigned int)(g + 1) * GAP;
        gend = (gend > 9215u) ? 9215u : gend;
        const unsigned int width = (Lb + gend) - gstart;  // 143 or 144
        const int m_glo = __shfl(mprev, g);               // mask at gstart
        int mk0 = predmask16(__uint_as_float(gstart + 1u + (unsigned int)l), hh, TT);
        int mk1 = predmask16(__uint_as_float(gstart + 65u + (unsigned int)l), hh, TT);
        int mk2 = predmask16(__uint_as_float(gstart + 129u + (unsigned int)l), hh, TT);
        int pm0 = __shfl_up(mk0, 1);
        int pm1 = __shfl_up(mk1, 1);
        int pm2 = __shfl_up(mk2, 1);
        const int w0 = __shfl(mk0, 63);
        const int w1 = __shfl(mk1, 63);
        if (l == 0) { pm0 = m_glo; pm1 = w0; pm2 = w1; }
        if ((unsigned int)l < width && pm0 != mk0) {
            int s = atomicAdd(&cntS, 1);
            if (s <= CMAX) { posS[s] = gstart + 1u + l; mskS[s] = mk0; }
        }
        if ((unsigned int)(l + 64) < width && pm1 != mk1) {
            int s = atomicAdd(&cntS, 1);
            if (s <= CMAX) { posS[s] = gstart + 65u + l; mskS[s] = mk1; }
        }
        if ((unsigned int)(l + 128) < width && pm2 != mk2) {
            int s = atomicAdd(&cntS, 1);
            if (s <= CMAX) { posS[s] = gstart + 129u + l; mskS[s] = mk2; }
        }
        __syncthreads();
    }
    __syncthreads();

    if (l == 0) {
        int c = cntS;
        if (c < 1 || c > CMAX) {
            atomicOr(&ws[W_FLAG], 1u);
            ws[W_LUT + b] = 0u;
        } else {
            for (int i = 1; i < c; ++i) {  // insertion sort by position
                unsigned int p = posS[i];
                int m = mskS[i];
                int j = i - 1;
                while (j >= 0 && posS[j] > p) {
                    posS[j + 1] = posS[j];
                    mskS[j + 1] = mskS[j];
                    --j;
                }
                posS[j + 1] = p;
                mskS[j + 1] = m;
            }
            const unsigned int need = 2u * (unsigned int)c + 1u;
            const unsigned int start = atomicAdd(&ws[W_CNT], need);
            if (start + need > BP_CAP) {
                atomicOr(&ws[W_FLAG], 1u);
                ws[W_LUT + b] = 0u;
            } else {
                for (int k = 0; k < c; ++k) ws[W_BP + start + k] = posS[k];
                ws[W_BP + start + c] = valbits(mL, dd);
                for (int j = 0; j < c; ++j)
                    ws[W_BP + start + c + 1 + j] = valbits(mskS[j], dd);
                ws[W_LUT + b] = 0x7F800000u | ((unsigned int)c << 19) | start;
            }
        }
    }
}

// ----------------------------------------------------------------- K3: apply
__device__ __forceinline__ float lut_elem(float xe,
                                          const unsigned int* __restrict__ lutS,
                                          const unsigned int* __restrict__ bpS,
                                          unsigned int lo_e, unsigned int hi_e) {
    const unsigned int u = __float_as_uint(xe);
    const unsigned int sb = u & 0x80000000u;
    const unsigned int ab = u & 0x7FFFFFFFu;
    unsigned int t = ab - BIN_B0;                    // wraps if ab < B0
    t = (t > BIN_RANGE - 1u) ? (BIN_RANGE - 1u) : t; // clamp wrap / high
    const unsigned int bin = ((t >> 10) * 58255u) >> 19;  // exact floor(/9216)
    unsigned int eb = lutS[bin];
    eb = (ab < BIN_B0) ? lo_e : eb;
    eb = (ab >= BIN_B1) ? hi_e : eb;
    if ((eb & 0x7F800000u) == 0x7F800000u) {  // multi-segment bin record
        const unsigned int s = eb & 0x7FFFFu;
        const unsigned int c = (eb >> 19) & 0xFu;
        unsigned int j = 0;
        for (unsigned int k = 0; k < c; ++k)
            j += (ab >= bpS[s + k]) ? 1u : 0u;   // bps sorted; j = rank
        eb = bpS[s + c + j];
    }
    const float r = __uint_as_float(eb ^ sb);
    return (xe == 0.0f) ? 0.0f : r;
}

__global__ __launch_bounds__(256) void snn_apply(
    const float* __restrict__ x, const float* __restrict__ h,
    const float* __restrict__ d, const float* __restrict__ T,
    float* __restrict__ out, const unsigned int* __restrict__ ws,
    int n8, int n4, int n) {
    __shared__ unsigned int lutS[NBIN];   // 16 KB
    __shared__ unsigned int bpS[BP_CAP];  // 8 KB
    const int tid = threadIdx.x;

    for (int i = tid; i < NBIN; i += 256) lutS[i] = ws[W_LUT + i];
    for (int i = tid; i < BP_CAP; i += 256) bpS[i] = ws[W_BP + i];
    const unsigned int flag = ws[W_FLAG];
    const unsigned int lo_e = ws[W_LO];
    const unsigned int hi_e = ws[W_HI];
    __syncthreads();

    const float4* __restrict__ x4 = reinterpret_cast<const float4*>(x);
    float4* __restrict__ o4 = reinterpret_cast<float4*>(out);
    const int gtid = blockIdx.x * blockDim.x + tid;
    const int nt = gridDim.x * blockDim.x;

    if (flag == 0u) {  // ---- LUT path (expected) ----
#define APPLY4(vv)                                                             \
        {                                                                      \
            float4 ov;                                                         \
            ov.x = lut_elem(vv.x, lutS, bpS, lo_e, hi_e);                      \
            ov.y = lut_elem(vv.y, lutS, bpS, lo_e, hi_e);                      \
            ov.z = lut_elem(vv.z, lutS, bpS, lo_e, hi_e);                      \
            ov.w = lut_elem(vv.w, lutS, bpS, lo_e, hi_e);                      \
            vv = ov;                                                           \
        }
        int i = gtid;  // unit = pair of adjacent float4 (R4 skeleton)
        if (i < n8) {
            float4 ca = x4[2 * i], cb = x4[2 * i + 1];
            int nx = i + nt;
            while (nx < n8) {
                float4 pa = x4[2 * nx], pb = x4[2 * nx + 1];
                APPLY4(ca); APPLY4(cb);
                o4[2 * i] = ca; o4[2 * i + 1] = cb;
                ca = pa; cb = pb;
                i = nx; nx += nt;
            }
            APPLY4(ca); APPLY4(cb);
            o4[2 * i] = ca; o4[2 * i + 1] = cb;
        }
        for (int j = n8 * 2 + gtid; j < n4; j += nt) {
            float4 v = x4[j];
            APPLY4(v);
            o4[j] = v;
        }
        for (int j = n4 * 4 + gtid; j < n; j += nt)
            out[j] = lut_elem(x[j], lutS, bpS, lo_e, hi_e);
#undef APPLY4
    } else {  // ---- wave-uniform fallback: direct scan (always correct) ----
        float hh[16], dd[16], TT[16];
#pragma unroll
        for (int k = 0; k < 16; ++k) { hh[k] = h[k]; dd[k] = d[k]; TT[k] = T[k]; }
        for (int j = gtid; j < n4; j += nt) {
            float4 v = x4[j], ov;
            float* pi = &v.x;
            float* po = &ov.x;
#pragma unroll
            for (int e = 0; e < 4; ++e) {
                float xe = pi[e];
                float acc = scan_exact(__float_as_uint(xe) & 0x7FFFFFFFu, hh, dd, TT);
                unsigned int rb =
                    __float_as_uint(acc) ^ (__float_as_uint(xe) & 0x80000000u);
                po[e] = (xe == 0.0f) ? 0.0f : __uint_as_float(rb);
            }
            o4[j] = ov;
        }
        for (int j = n4 * 4 + gtid; j < n; j += nt) {
            float xe = x[j];
            float acc = scan_exact(__float_as_uint(xe) & 0x7FFFFFFFu, hh, dd, TT);
            unsigned int rb = __float_as_uint(acc) ^ (__float_as_uint(xe) & 0x80000000u);
            out[j] = (xe == 0.0f) ? 0.0f : __uint_as_float(rb);
        }
    }
}

// -------------------------------------------- direct fallback (ws too small)
__global__ __launch_bounds__(256) void snn_direct(
    const float* __restrict__ x, const float* __restrict__ h,
    const float* __restrict__ d, const float* __restrict__ T,
    float* __restrict__ out, int n4, int n) {
    float hh[16], dd[16], TT[16];
#pragma unroll
    for (int k = 0; k < 16; ++k) { hh[k] = h[k]; dd[k] = d[k]; TT[k] = T[k]; }
    const float4* __restrict__ x4 = reinterpret_cast<const float4*>(x);
    float4* __restrict__ o4 = reinterpret_cast<float4*>(out);
    const int gtid = blockIdx.x * blockDim.x + threadIdx.x;
    const int nt = gridDim.x * blockDim.x;
    for (int i = gtid; i < n4; i += nt) {
        float4 v = x4[i], ov;
        float* pi = &v.x;
        float* po = &ov.x;
#pragma unroll
        for (int e = 0; e < 4; ++e) {
            float xe = pi[e];
            float acc = scan_exact(__float_as_uint(xe) & 0x7FFFFFFFu, hh, dd, TT);
            unsigned int rb =
                __float_as_uint(acc) ^ (__float_as_uint(xe) & 0x80000000u);
            po[e] = (xe == 0.0f) ? 0.0f : __uint_as_float(rb);
        }
        o4[i] = ov;
    }
    for (int j = n4 * 4 + gtid; j < n; j += nt) {
        float xe = x[j];
        float acc = scan_exact(__float_as_uint(xe) & 0x7FFFFFFFu, hh, dd, TT);
        unsigned int rb = __float_as_uint(acc) ^ (__float_as_uint(xe) & 0x80000000u);
        out[j] = (xe == 0.0f) ? 0.0f : __uint_as_float(rb);
    }
}

extern "C" void kernel_launch(void* const* d_in, const int* in_sizes, int n_in,
                              void* d_out, int out_size, void* d_ws, size_t ws_size,
                              hipStream_t stream) {
    const float* x = (const float*)d_in[0];
    const float* h = (const float*)d_in[1];
    const float* d = (const float*)d_in[2];
    const float* T = (const float*)d_in[3];
    float* out = (float*)d_out;

    const int n = in_sizes[0];
    const int n4 = n / 4;
    const int n8 = n / 8;

    if (ws_size < (size_t)WS_WORDS * 4) {
        int grid = 2048;
        const int needed = (n4 + 255) / 256;
        if (grid > needed) grid = needed > 0 ? needed : 1;
        snn_direct<<<grid, 256, 0, stream>>>(x, h, d, T, out, n4, n);
        return;
    }

    unsigned int* ws = (unsigned int*)d_ws;
    snn_classify<<<NBIN / 256, 256, 0, stream>>>(h, d, T, ws);
    snn_refine<<<NBIN, 64, 0, stream>>>(h, d, T, ws);

    // 24 KB LDS/block -> 6 blocks/CU -> 1536 blocks fills the chip.
    int grid = 1536;
    const int needed = (n8 + 255) / 256;
    if (grid > needed) grid = needed > 0 ? needed : 1;
    snn_apply<<<grid, 256, 0, stream>>>(x, h, d, T, out, ws, n8, n4, n);
}